// Round 1
// 110.488 us; speedup vs baseline: 1.0681x; 1.0681x over previous
//
#include <hip/hip_runtime.h>
#include <math.h>
#include <stdint.h>

#define D 4096
#define H 32
#define KVH 8
#define HD 128
#define B_ 8
#define SEQ 16
#define MAXLEN 2048
#define NTOK 128          // B_*SEQ
#define KSPLIT 8
#define KCH 512           // D / KSPLIT
#define BK 64
#define NSTEP (KCH / BK)  // 8
#define KSA 16            // attention key-split across blocks (merged by attn_merge)

typedef __attribute__((ext_vector_type(8))) short bh8;    // 8 bf16 (4 VGPRs)
typedef __attribute__((ext_vector_type(4))) float f32x4;  // MFMA C/D frag
typedef _Float16 f16x2 __attribute__((ext_vector_type(2)));
typedef _Float16 f16x8 __attribute__((ext_vector_type(8)));

static __device__ __forceinline__ int imin(int a, int b) { return a < b ? a : b; }

static __device__ __forceinline__ short f2bf(float x) {   // RNE f32 -> bf16 bits
    union { float f; uint32_t u; } v; v.f = x;
    uint32_t u = v.u;
    return (short)((u + 0x7fffu + ((u >> 16) & 1u)) >> 16);
}
static __device__ __forceinline__ float bf2f(short b) {
    union { uint32_t u; float f; } v; v.u = ((uint32_t)(uint16_t)b) << 16;
    return v.f;
}

static __device__ __forceinline__ float fexp2(float x) {
#if __has_builtin(__builtin_amdgcn_exp2f)
    return __builtin_amdgcn_exp2f(x);
#else
    return exp2f(x);
#endif
}

static __device__ __forceinline__ void gll16(const void* g, void* l) {
    __builtin_amdgcn_global_load_lds((const __attribute__((address_space(1))) uint32_t*)g,
                                     (__attribute__((address_space(3))) uint32_t*)l, 16, 0, 0);
}

// x (128 x 4096 f32) -> bf16 in MFMA A-layout: xp[(kg*128 + row)*8 + j], k = kg*8+j.
__global__ __launch_bounds__(256) void cvt_x(const float* __restrict__ x, short* __restrict__ xp) {
    int i = blockIdx.x * 256 + threadIdx.x;   // 131072 float4s
    int row = i >> 10;
    int c4 = (i & 1023) << 2;                 // col, multiple of 4
    const float4 v = ((const float4*)x)[i];
    short4 o;
    o.x = f2bf(v.x); o.y = f2bf(v.y); o.z = f2bf(v.z); o.w = f2bf(v.w);
    *(short4*)&xp[((size_t)((c4 >> 3) * 128 + row)) * 8 + (c4 & 7)] = o;
}

// C_partial(bf16) = A(128 x K, bf16 pre-laid-out) @ W(K x ntot, f32 row-major).
//
// v2 (throughput rewrite): 512 threads (8 waves), N-tile 128, BK=64, KSPLIT=8.
//  - W path: float4 (dwordx4) loads, 512-B contiguous segments per wave-instr
//    (was float2 / 256-B), 4 vmem instr/thread/step (was 8).
//  - W staged in LDS col-major [col][68] bf16 (64 k + 4 pad halves):
//    B-frag = two ds_read_b64 at (col*68 + h*32 + kg*8), bank word = 2c+4g -> 4-way
//    (1.58x, cheap); writes are 4x ds_write_b64, 8-way conflict but off critical path.
//  - A path: global_load_lds width-16 (unchanged layout, linear dest rule honored:
//    dest = base + tid*16B).
//  - Pipeline: single __syncthreads per step, compiler-managed waits, NO inline asm.
//    Loads for t+1 issue before compute(t); cvt+LDS-write after compute(t); the
//    barrier's vmcnt(0)/lgkmcnt(0) drain is exactly the sync we need (m97 structure).
//  - Occupancy: LDS 66 KB -> 2 blocks/CU = 16 waves/CU; launch_bounds(512,4) caps
//    regs at 128 (est. ~100 incl. acc) so VGPR doesn't cut below 2 blocks.
__global__ __launch_bounds__(512, 4) void gemm_mfma(const short* __restrict__ xp,
                                                    const float* __restrict__ wq,
                                                    const float* __restrict__ wk,
                                                    const float* __restrict__ wv,
                                                    short* __restrict__ Pq,
                                                    short* __restrict__ Pk,
                                                    short* __restrict__ Pv) {
    const int cbid = blockIdx.x;
    const int ks = blockIdx.y;
    const float* W; short* P; int ntot; int cb;
    if (cbid < 32)      { W = wq; P = Pq; ntot = 4096; cb = cbid * 128; }
    else if (cbid < 40) { W = wk; P = Pk; ntot = 1024; cb = (cbid - 32) * 128; }
    else                { W = wv; P = Pv; ntot = 1024; cb = (cbid - 40) * 128; }
    const int tid = threadIdx.x;              // 0..511
    const int lane = tid & 63;
    const int w = tid >> 6;                   // wave 0..7
    const int wm = w >> 1, wn = w & 1;        // wave tile: rows wm*32, cols wn*64
    const int lrow = lane & 15, lkg = lane >> 4;
    const int k0 = ks * KCH;

    __shared__ __align__(16) short Asm[2][8192];      // [kg8][row128][8] halves, 16KB/buf
    __shared__ __align__(16) short Wsm[2][128 * 68];  // [col128][68] halves,   17KB/buf

    f32x4 acc[2][4];
#pragma unroll
    for (int fm = 0; fm < 2; ++fm)
#pragma unroll
        for (int fn = 0; fn < 4; ++fn) acc[fm][fn] = (f32x4){0.f, 0.f, 0.f, 0.f};

    // W-load mapping: thread covers cols c4..c4+3, rows kq*4..kq*4+3 of the 64x128 tile.
    const int c4 = (tid & 31) * 4;            // 0..124
    const int kq = tid >> 5;                  // 0..15

    float wrf[16];                            // 4 rows x 4 cols, raw f32 (convert-late)
    auto loadW = [&](int t) {
        const float* p = W + (size_t)(k0 + t * BK + kq * 4) * ntot + cb + c4;
#pragma unroll
        for (int j = 0; j < 4; ++j) *(float4*)&wrf[j * 4] = *(const float4*)(p + (size_t)j * ntot);
    };
    auto writeW = [&](int bufw) {             // per col: 4 k-contiguous bf16 -> ds_write_b64
#pragma unroll
        for (int u = 0; u < 4; ++u) {
            short4 o;
            o.x = f2bf(wrf[0 * 4 + u]);
            o.y = f2bf(wrf[1 * 4 + u]);
            o.z = f2bf(wrf[2 * 4 + u]);
            o.w = f2bf(wrf[3 * 4 + u]);
            *(short4*)&Wsm[bufw][(c4 + u) * 68 + kq * 4] = o;
        }
    };
    auto loadA = [&](int t, int bufa) {       // 16 KB: 2 glls x 512 threads x 16 B
        const short* ap = xp + (size_t)(k0 >> 3) * 1024 + (size_t)t * 8192 + (size_t)tid * 8;
        short* ad = &Asm[bufa][tid * 8];
        gll16(ap, ad);
        gll16(ap + 4096, ad + 4096);
    };
    auto compute = [&](int bufc) {
#pragma unroll
        for (int h = 0; h < 2; ++h) {
            bh8 afr[2];
#pragma unroll
            for (int fm = 0; fm < 2; ++fm)
                afr[fm] = *(const bh8*)&Asm[bufc][((h * 4 + lkg) * 128 + wm * 32 + fm * 16 + lrow) * 8];
#pragma unroll
            for (int fn = 0; fn < 4; ++fn) {
                const short* bp = &Wsm[bufc][(wn * 64 + fn * 16 + lrow) * 68 + h * 32 + lkg * 8];
                const short4 lo = *(const short4*)bp;
                const short4 hi = *(const short4*)(bp + 4);
                const bh8 bfr = (bh8){lo.x, lo.y, lo.z, lo.w, hi.x, hi.y, hi.z, hi.w};
#pragma unroll
                for (int fm = 0; fm < 2; ++fm)
                    acc[fm][fn] = __builtin_amdgcn_mfma_f32_16x16x32_bf16(afr[fm], bfr, acc[fm][fn], 0, 0, 0);
            }
        }
    };

    loadA(0, 0);
    loadW(0);
    writeW(0);                 // auto-waits the W regs (once, prologue)
    __syncthreads();           // drains gll(0) + lgkm

    int buf = 0;
    for (int t = 0; t < NSTEP; ++t) {
        if (t + 1 < NSTEP) { loadA(t + 1, buf ^ 1); loadW(t + 1); }  // issue early
        compute(buf);
        if (t + 1 < NSTEP) writeW(buf ^ 1);   // convert-late; W regs had compute-time to land
        __syncthreads();                      // drains gll(t+1) + ds_writes
        buf ^= 1;
    }

    short* pp = P + (size_t)ks * NTOK * ntot;
#pragma unroll
    for (int fm = 0; fm < 2; ++fm) {
        const int gr0 = wm * 32 + fm * 16 + lkg * 4;
#pragma unroll
        for (int fn = 0; fn < 4; ++fn) {
            const int gc = cb + wn * 64 + fn * 16 + lrow;
#pragma unroll
            for (int q = 0; q < 4; ++q)
                pp[(size_t)(gr0 + q) * ntot + gc] = f2bf(acc[fm][fn][q]);
        }
    }
}

// Sum K-split bf16 partials of Q/K/V; apply interleaved-pair rotary to q and k_new.
__global__ __launch_bounds__(256) void combine_rot(const short* __restrict__ Pq,
                                                   const short* __restrict__ Pk,
                                                   const short* __restrict__ Pv,
                                                   float* __restrict__ qb,
                                                   float* __restrict__ knb,
                                                   float* __restrict__ vnb,
                                                   const float* __restrict__ cosT,
                                                   const float* __restrict__ sinT,
                                                   const int* __restrict__ startp) {
    int gid = blockIdx.x * 256 + threadIdx.x;
    int tok = gid / 3072;
    int pr = gid % 3072;
    int col = pr * 2;
    int start = *startp;
    int pos = start + (tok & (SEQ - 1));
    float a = 0.f, b = 0.f;
    if (col < 4096) {
        const short* base = Pq + (size_t)tok * 4096 + col;
#pragma unroll
        for (int ks = 0; ks < KSPLIT; ++ks) {
            short2 t = *(const short2*)(base + (size_t)ks * NTOK * 4096);
            a += bf2f(t.x); b += bf2f(t.y);
        }
        int i = (col & 127) >> 1;
        float c = cosT[pos * 64 + i], s = sinT[pos * 64 + i];
        qb[(size_t)tok * 4096 + col]     = a * c - b * s;
        qb[(size_t)tok * 4096 + col + 1] = a * s + b * c;
    } else if (col < 5120) {
        int colr = col - 4096;
        const short* base = Pk + (size_t)tok * 1024 + colr;
#pragma unroll
        for (int ks = 0; ks < KSPLIT; ++ks) {
            short2 t = *(const short2*)(base + (size_t)ks * NTOK * 1024);
            a += bf2f(t.x); b += bf2f(t.y);
        }
        int i = (colr & 127) >> 1;
        float c = cosT[pos * 64 + i], s = sinT[pos * 64 + i];
        knb[(size_t)tok * 1024 + colr]     = a * c - b * s;
        knb[(size_t)tok * 1024 + colr + 1] = a * s + b * c;
    } else {
        int colr = col - 5120;
        const short* base = Pv + (size_t)tok * 1024 + colr;
#pragma unroll
        for (int ks = 0; ks < KSPLIT; ++ks) {
            short2 t = *(const short2*)(base + (size_t)ks * NTOK * 1024);
            a += bf2f(t.x); b += bf2f(t.y);
        }
        vnb[(size_t)tok * 1024 + colr]     = a;
        vnb[(size_t)tok * 1024 + colr + 1] = b;
    }
}

// MFMA attention partial pass. grid (ksb, kvh, b) = (16,8,8); block = 256 = 4 waves.
// S^T = mfma(A=K, B=Q^T) with key permutation (softmax + P^T lane-local);
// PV: O^T = mfma(A=V^T, B=P^T).
// T14 STAGE SPLIT: gloadRaw issues pure f32 loads (no cvt) BEFORE compute;
// cvtStore converts+writes LDS AFTER compute, so HBM latency hides under MFMA.
__global__ __launch_bounds__(256) void attn_fused(const float* __restrict__ qb,
                                                  const float* __restrict__ knb,
                                                  const float* __restrict__ vnb,
                                                  const float* __restrict__ ck,
                                                  const float* __restrict__ cv,
                                                  short* __restrict__ Opart,
                                                  float* __restrict__ mpart,
                                                  float* __restrict__ lpart,
                                                  const int* __restrict__ startp) {
    const int ksb = blockIdx.x;
    const int kvh = blockIdx.y;
    const int b   = blockIdx.z;
    const int start = *startp;
    const int klen = start + SEQ;
    const int chunk = (klen + KSA - 1) / KSA;        // 65
    const int bbeg = ksb * chunk;
    const int bend = imin(bbeg + chunk, klen);
    const int tiles = (chunk + 31) >> 5;             // 3, uniform across waves/blocks

    const int tid = threadIdx.x;
    const int w = tid >> 6, lane = tid & 63;
    const int c = lane & 15, g = lane >> 4;
    const int hh = kvh * 4 + w;

    __shared__ __align__(16) _Float16 Ksh[2][16][32][8];   // [buf][dg][slot][8] 16KB
    __shared__ __align__(16) _Float16 Vsh[2][4][128][8];   // [buf][kg][d][key&7] 16KB

    const float scl2 = 0.08838834764831843f * 1.4426950408889634f;  // 1/sqrt(128)*log2e

    // Q fragments (B-operand): qfr[h][j] = Q[tok=c][32h+8g+j] * scl2, f16
    f16x8 qfr[4];
    {
        const float* qp = qb + (size_t)(b * SEQ + c) * 4096 + hh * 128 + 8 * g;
#pragma unroll
        for (int h = 0; h < 4; ++h) {
            float4 a = *(const float4*)(qp + 32 * h);
            float4 b2 = *(const float4*)(qp + 32 * h + 4);
            qfr[h][0] = (_Float16)(a.x * scl2);  qfr[h][1] = (_Float16)(a.y * scl2);
            qfr[h][2] = (_Float16)(a.z * scl2);  qfr[h][3] = (_Float16)(a.w * scl2);
            qfr[h][4] = (_Float16)(b2.x * scl2); qfr[h][5] = (_Float16)(b2.y * scl2);
            qfr[h][6] = (_Float16)(b2.z * scl2); qfr[h][7] = (_Float16)(b2.w * scl2);
        }
    }

    f32x4 acc_o[8];
#pragma unroll
    for (int dm = 0; dm < 8; ++dm) acc_o[dm] = (f32x4){0.f, 0.f, 0.f, 0.f};
    float mrun = -INFINITY, lrun = 0.f;

    // staging geometry: K slot s holds physical key 8*((s>>2)&3)+4*(s>>4)+(s&3)
    const int s_   = tid & 31;
    const int dgA  = tid >> 5;             // 0..7
    const int koffK = 8 * ((s_ >> 2) & 3) + 4 * (s_ >> 4) + (s_ & 3);
    const int kg0 = tid >> 6, d0 = (tid & 63) * 2;

    // RAW f32 staging registers — loads issue here, conversion deferred to cvtStore
    float4 kr0, kr1, kr2, kr3;
    float2 vrw[8];
    auto gloadRaw = [&](int t) {
        const int kp = bbeg + t * 32 + koffK;
        kr0 = (float4){0.f,0.f,0.f,0.f}; kr1 = kr0; kr2 = kr0; kr3 = kr0;
        if (kp < bend) {
            const float* kr = (kp < start)
                ? ck + ((size_t)((b * MAXLEN + kp) * KVH + kvh)) * HD
                : knb + (size_t)(b * SEQ + kp - start) * 1024 + kvh * HD;
            kr0 = *(const float4*)(kr + dgA * 8);
            kr1 = *(const float4*)(kr + dgA * 8 + 4);
            kr2 = *(const float4*)(kr + dgA * 8 + 64);
            kr3 = *(const float4*)(kr + dgA * 8 + 68);
        }
#pragma unroll
        for (int j = 0; j < 8; ++j) {
            const int kpv = bbeg + t * 32 + kg0 * 8 + j;
            vrw[j] = (float2){0.f, 0.f};
            if (kpv < bend) {
                const float* vrp = (kpv < start)
                    ? cv + ((size_t)((b * MAXLEN + kpv) * KVH + kvh)) * HD + d0
                    : vnb + (size_t)(b * SEQ + kpv - start) * 1024 + kvh * HD + d0;
                vrw[j] = *(const float2*)vrp;
            }
        }
    };
    auto cvtStore = [&](int bf) {          // convert-late + LDS write
        f16x8 ka, kb;
        ka[0]=(_Float16)kr0.x; ka[1]=(_Float16)kr0.y; ka[2]=(_Float16)kr0.z; ka[3]=(_Float16)kr0.w;
        ka[4]=(_Float16)kr1.x; ka[5]=(_Float16)kr1.y; ka[6]=(_Float16)kr1.z; ka[7]=(_Float16)kr1.w;
        kb[0]=(_Float16)kr2.x; kb[1]=(_Float16)kr2.y; kb[2]=(_Float16)kr2.z; kb[3]=(_Float16)kr2.w;
        kb[4]=(_Float16)kr3.x; kb[5]=(_Float16)kr3.y; kb[6]=(_Float16)kr3.z; kb[7]=(_Float16)kr3.w;
        *(f16x8*)&Ksh[bf][dgA][s_][0] = ka;
        *(f16x8*)&Ksh[bf][dgA + 8][s_][0] = kb;
        f16x8 w0, w1;
#pragma unroll
        for (int j = 0; j < 8; ++j) { w0[j] = (_Float16)vrw[j].x; w1[j] = (_Float16)vrw[j].y; }
        *(f16x8*)&Vsh[bf][kg0][d0][0] = w0;
        *(f16x8*)&Vsh[bf][kg0][d0 + 1][0] = w1;
    };

    gloadRaw(0);
    cvtStore(0);
    __syncthreads();

    int buf = 0;
    for (int t = 0; t < tiles; ++t) {
        if (t + 1 < tiles) gloadRaw(t + 1);        // pure loads, in flight under compute
        const int nk = imin(32, bend - (bbeg + t * 32));

        f32x4 acc_s[2];
        acc_s[0] = (f32x4){0.f, 0.f, 0.f, 0.f};
        acc_s[1] = (f32x4){0.f, 0.f, 0.f, 0.f};
#pragma unroll
        for (int h = 0; h < 4; ++h) {
#pragma unroll
            for (int m = 0; m < 2; ++m) {
                const f16x8 afr = *(const f16x8*)&Ksh[buf][h * 4 + g][m * 16 + c][0];
                acc_s[m] = __builtin_amdgcn_mfma_f32_16x16x32_f16(afr, qfr[h], acc_s[m], 0, 0, 0);
            }
        }
        float s8[8];
#pragma unroll
        for (int m = 0; m < 2; ++m)
#pragma unroll
            for (int q = 0; q < 4; ++q) s8[m * 4 + q] = acc_s[m][q];
        if (nk < 32) {
#pragma unroll
            for (int jj = 0; jj < 8; ++jj)
                if (8 * g + jj >= nk) s8[jj] = -1e30f;
        }
        float tmax = s8[0];
#pragma unroll
        for (int jj = 1; jj < 8; ++jj) tmax = fmaxf(tmax, s8[jj]);
        tmax = fmaxf(tmax, __shfl_xor(tmax, 16));
        tmax = fmaxf(tmax, __shfl_xor(tmax, 32));     // row max across the 4 g-lanes
        if (__any(tmax > mrun + 11.5f)) {             // sticky max (T13)
            const float mn = fmaxf(mrun, tmax);
            const float fac = fexp2(mrun - mn);
            lrun *= fac;
#pragma unroll
            for (int dm = 0; dm < 8; ++dm) {
                acc_o[dm][0] *= fac; acc_o[dm][1] *= fac;
                acc_o[dm][2] *= fac; acc_o[dm][3] *= fac;
            }
            mrun = mn;
        }
        float pe[8];
#pragma unroll
        for (int jj = 0; jj < 8; ++jj) pe[jj] = fexp2(s8[jj] - mrun);
#pragma unroll
        for (int jj = 0; jj < 8; ++jj) lrun += pe[jj];
        f16x8 bp;
#pragma unroll
        for (int jj = 0; jj < 8; ++jj) bp[jj] = (_Float16)pe[jj];

#pragma unroll
        for (int dm = 0; dm < 8; ++dm) {
            const f16x8 av = *(const f16x8*)&Vsh[buf][g][dm * 16 + c][0];
            acc_o[dm] = __builtin_amdgcn_mfma_f32_16x16x32_f16(av, bp, acc_o[dm], 0, 0, 0);
        }

        if (t + 1 < tiles) cvtStore(buf ^ 1);      // counted wait lands AFTER compute
        __syncthreads();
        buf ^= 1;
    }

    lrun += __shfl_xor(lrun, 16);
    lrun += __shfl_xor(lrun, 32);

    const int base = ((b * KVH + kvh) * KSA + ksb) * 64;
    const int row = w * 16 + c;
#pragma unroll
    for (int dm = 0; dm < 8; ++dm) {
        short4 o4;
        o4.x = f2bf(acc_o[dm][0]); o4.y = f2bf(acc_o[dm][1]);
        o4.z = f2bf(acc_o[dm][2]); o4.w = f2bf(acc_o[dm][3]);
        *(short4*)&Opart[(size_t)(base + row) * 128 + dm * 16 + g * 4] = o4;
    }
    if (g == 0) { mpart[base + row] = mrun; lpart[base + row] = lrun; }
}

// Merge KSA partials -> aob (bf16, out-proj A-layout). m/l are exp2-domain.
__global__ __launch_bounds__(256) void attn_merge(const short* __restrict__ Opart,
                                                  const float* __restrict__ mpart,
                                                  const float* __restrict__ lpart,
                                                  short* __restrict__ aob) {
    const int bkvh = blockIdx.x;
    const int tid = threadIdx.x;
    __shared__ float sf[KSA][64];
    __shared__ float sinvL[64];
    if (tid < 64) {
        const int row = tid;
        float M = -INFINITY;
#pragma unroll
        for (int ks = 0; ks < KSA; ++ks)
            M = fmaxf(M, mpart[(size_t)(bkvh * KSA + ks) * 64 + row]);
        float L = 0.f;
#pragma unroll
        for (int ks = 0; ks < KSA; ++ks) {
            float f = exp2f(mpart[(size_t)(bkvh * KSA + ks) * 64 + row] - M);
            sf[ks][row] = f;
            L += f * lpart[(size_t)(bkvh * KSA + ks) * 64 + row];
        }
        sinvL[row] = 1.f / L;
    }
    __syncthreads();
    const int b = bkvh >> 3, kvh = bkvh & 7;
    for (int e = tid; e < 2048; e += 256) {
        const int row = e >> 5;
        const int d4 = (e & 31) << 2;
        float a0 = 0.f, a1 = 0.f, a2 = 0.f, a3 = 0.f;
#pragma unroll
        for (int ks = 0; ks < KSA; ++ks) {
            const short4 sp = *(const short4*)&Opart[((size_t)(bkvh * KSA + ks) * 64 + row) * 128 + d4];
            const float f = sf[ks][row];
            a0 = fmaf(f, bf2f(sp.x), a0);
            a1 = fmaf(f, bf2f(sp.y), a1);
            a2 = fmaf(f, bf2f(sp.z), a2);
            a3 = fmaf(f, bf2f(sp.w), a3);
        }
        const float iL = sinvL[row];
        a0 *= iL; a1 *= iL; a2 *= iL; a3 *= iL;
        const int hh = kvh * 4 + (row >> 4);
        const int tok = b * SEQ + (row & 15);
        const int col = hh * 128 + d4;
        short4 o;
        o.x = f2bf(a0); o.y = f2bf(a1); o.z = f2bf(a2); o.w = f2bf(a3);
        *(short4*)&aob[((size_t)(col >> 3) * 128 + tok) * 8 + (col & 7)] = o;
    }
}

// Sum the KSPLIT bf16 out-proj partials into f32 d_out.
__global__ __launch_bounds__(256) void sum_parts(const short* __restrict__ P,
                                                 float* __restrict__ out) {
    int i = blockIdx.x * 256 + threadIdx.x;     // over groups of 4 elems, 131072 total
    float a0 = 0.f, a1 = 0.f, a2 = 0.f, a3 = 0.f;
#pragma unroll
    for (int ks = 0; ks < KSPLIT; ++ks) {
        const short4 t = ((const short4*)(P + (size_t)ks * NTOK * 4096))[i];
        a0 += bf2f(t.x); a1 += bf2f(t.y); a2 += bf2f(t.z); a3 += bf2f(t.w);
    }
    ((float4*)out)[i] = make_float4(a0, a1, a2, a3);
}

extern "C" void kernel_launch(void* const* d_in, const int* in_sizes, int n_in,
                              void* d_out, int out_size, void* d_ws, size_t ws_size,
                              hipStream_t stream) {
    const float* x  = (const float*)d_in[0];
    const float* wq = (const float*)d_in[1];
    const float* wk = (const float*)d_in[2];
    const float* wv = (const float*)d_in[3];
    const float* wo = (const float*)d_in[4];
    const float* cs = (const float*)d_in[5];
    const float* sn = (const float*)d_in[6];
    const float* ck = (const float*)d_in[7];
    const float* cv = (const float*)d_in[8];
    const int* startp = (const int*)d_in[9];

    // ws layout (bf16 partials). Opart (16.8MB) overlays Pqb+Pkb+Pvb (12.6MB) plus
    // 4.2MB of pad; all live buffers start after Opart's full extent.
    short* Opart = (short*)d_ws;                              // 64*16*64*128 shorts
    short* Pqb = Opart;                                       // dead by attn time
    short* Pkb = Pqb + (size_t)KSPLIT * NTOK * 4096;
    short* Pvb = Pkb + (size_t)KSPLIT * NTOK * 1024;
    float* qb   = (float*)(Opart + (size_t)64 * KSA * 64 * 128);  // after 16.8MB
    float* knb  = qb + (size_t)NTOK * 4096;
    float* vnb  = knb + (size_t)NTOK * 1024;
    short* xpre = (short*)(vnb + (size_t)NTOK * 1024);
    short* aob  = xpre + (size_t)NTOK * 4096;
    float* mpart = (float*)(aob + (size_t)NTOK * 4096);
    float* lpart = mpart + (size_t)64 * KSA * 64;
    // total ws ~22.3MB

    cvt_x<<<512, 256, 0, stream>>>(x, xpre);
    // QKV: 32 Q col-blocks (NT=128) + 8 K + 8 V, x KSPLIT
    gemm_mfma<<<dim3(48, KSPLIT), 512, 0, stream>>>(xpre, wq, wk, wv, Pqb, Pkb, Pvb);
    combine_rot<<<1536, 256, 0, stream>>>(Pqb, Pkb, Pvb, qb, knb, vnb, cs, sn, startp);
    attn_fused<<<dim3(KSA, KVH, B_), 256, 0, stream>>>(qb, knb, vnb, ck, cv, Opart, mpart, lpart, startp);
    attn_merge<<<64, 256, 0, stream>>>(Opart, mpart, lpart, aob);
    // out-proj: 32 col-blocks (NT=128) x KSPLIT, all take the Q branch (W=wo)
    gemm_mfma<<<dim3(32, KSPLIT), 512, 0, stream>>>(aob, wo, wo, wo, Pqb, Pqb, Pqb);
    sum_parts<<<512, 256, 0, stream>>>(Pqb, (float*)d_out);
}

// Round 2
// 106.060 us; speedup vs baseline: 1.1127x; 1.0418x over previous
//
#include <hip/hip_runtime.h>
#include <math.h>
#include <stdint.h>

#define D 4096
#define H 32
#define KVH 8
#define HD 128
#define B_ 8
#define SEQ 16
#define MAXLEN 2048
#define NTOK 128          // B_*SEQ
#define KSPLIT 8
#define KCH 512           // D / KSPLIT
#define BK 32
#define TSTEPS (KCH / BK) // 16
#define KSA 16            // attention key-split across blocks (merged by attn_merge)

typedef __attribute__((ext_vector_type(8))) short bh8;    // 8 bf16 (4 VGPRs)
typedef __attribute__((ext_vector_type(4))) float f32x4;  // MFMA C/D frag
typedef _Float16 f16x2 __attribute__((ext_vector_type(2)));
typedef _Float16 f16x8 __attribute__((ext_vector_type(8)));

static __device__ __forceinline__ int imin(int a, int b) { return a < b ? a : b; }

static __device__ __forceinline__ short f2bf(float x) {   // RNE f32 -> bf16 bits
    union { float f; uint32_t u; } v; v.f = x;
    uint32_t u = v.u;
    return (short)((u + 0x7fffu + ((u >> 16) & 1u)) >> 16);
}
static __device__ __forceinline__ float bf2f(short b) {
    union { uint32_t u; float f; } v; v.u = ((uint32_t)(uint16_t)b) << 16;
    return v.f;
}

static __device__ __forceinline__ float fexp2(float x) {
#if __has_builtin(__builtin_amdgcn_exp2f)
    return __builtin_amdgcn_exp2f(x);
#else
    return exp2f(x);
#endif
}

// x (128 x 4096 f32) -> bf16 in MFMA A-layout: xp[(kg*128 + row)*8 + j], k = kg*8+j.
__global__ __launch_bounds__(256) void cvt_x(const float* __restrict__ x, short* __restrict__ xp) {
    int i = blockIdx.x * 256 + threadIdx.x;   // 131072 float4s
    int row = i >> 10;
    int c4 = (i & 1023) << 2;                 // col, multiple of 4
    const float4 v = ((const float4*)x)[i];
    short4 o;
    o.x = f2bf(v.x); o.y = f2bf(v.y); o.z = f2bf(v.z); o.w = f2bf(v.w);
    *(short4*)&xp[((size_t)((c4 >> 3) * 128 + row)) * 8 + (c4 & 7)] = o;
}

// C_partial(bf16) = A(128 x K, bf16 pre-laid-out) @ W(K x ntot, f32 row-major).
//
// v3 (barrier-free register-direct): the v1/v2 post-mortem showed ~2.2 TB/s
// invariant across two LDS-staged pipelines -> the per-step __syncthreads
// vmcnt(0) drain caps bytes-in-flight (Little's law). v3 removes LDS and
// barriers entirely:
//  - A-frags: per-thread bh8 (16 B) loads from xpre (L2-hot; wn-waves duplicate
//    reads -> 2x L2 traffic, acceptable).
//  - W B-frags: per-lane f32 dword loads, lanes coalesce to 4x64-B segments/instr;
//    raw f32 double-buffered in NAMED registers (no runtime indexing), convert
//    to bf16 at use (T14 convert-late).
//  - 20 vmem instrs (~8 KB) per wave per stage continuously in flight; the
//    compiler's per-register counted vmcnt never drains the queue.
//  - Wave tile 64x32 (fm=4, fn=2), NT=64, BK=32, 16 steps over KCH=512.
//  - LDS=0; occupancy VGPR-bound only (~12-16 waves/CU).
__global__ __launch_bounds__(256) void gemm_mfma(const short* __restrict__ xp,
                                                 const float* __restrict__ wq,
                                                 const float* __restrict__ wk,
                                                 const float* __restrict__ wv,
                                                 short* __restrict__ Pq,
                                                 short* __restrict__ Pk,
                                                 short* __restrict__ Pv) {
    const int cbid = blockIdx.x;
    const int ks = blockIdx.y;
    const float* W; short* P; int ntot; int cb;
    if (cbid < 64)      { W = wq; P = Pq; ntot = 4096; cb = cbid * 64; }
    else if (cbid < 80) { W = wk; P = Pk; ntot = 1024; cb = (cbid - 64) * 64; }
    else                { W = wv; P = Pv; ntot = 1024; cb = (cbid - 80) * 64; }
    const int tid = threadIdx.x;              // 0..255
    const int lane = tid & 63;
    const int w = tid >> 6;                   // wave 0..3
    const int wm = w >> 1, wn = w & 1;        // wave tile: rows wm*64, cols wn*32
    const int lrow = lane & 15, lkg = lane >> 4;
    const int k0 = ks * KCH;

    f32x4 acc[4][2];
#pragma unroll
    for (int fm = 0; fm < 4; ++fm)
#pragma unroll
        for (int fn = 0; fn < 2; ++fn) acc[fm][fn] = (f32x4){0.f, 0.f, 0.f, 0.f};

    // A: xp[(( (k0>>3) + t*4 + lkg )*128 + wm*64 + fm*16 + lrow)*8 + j]
    const short* abase = xp + ((size_t)((k0 >> 3) + lkg) * 128 + wm * 64 + lrow) * 8;
    // W: W[(k0 + t*32 + lkg*8 + j)*ntot + cb + wn*32 + fn*16 + lrow]
    const float* wbase = W + (size_t)(k0 + lkg * 8) * ntot + cb + wn * 32 + lrow;

    auto loadWf = [&](int t, float (&wr)[16]) {
        const float* p = wbase + (size_t)t * 32 * ntot;
#pragma unroll
        for (int j = 0; j < 8; ++j) {
            wr[j]     = p[0];    // fn = 0
            wr[8 + j] = p[16];   // fn = 1
            p += ntot;
        }
    };
    auto loadAf = [&](int t, bh8 (&ar)[4]) {
        const short* p = abase + (size_t)t * 4096;   // t*4 kgroups * 128 rows * 8
#pragma unroll
        for (int fm = 0; fm < 4; ++fm)
            ar[fm] = *(const bh8*)(p + fm * 128);
    };
    auto comp = [&](const bh8 (&ar)[4], const float (&wr)[16]) {
        bh8 bf0, bf1;
#pragma unroll
        for (int j = 0; j < 8; ++j) { bf0[j] = f2bf(wr[j]); bf1[j] = f2bf(wr[8 + j]); }
#pragma unroll
        for (int fm = 0; fm < 4; ++fm) {
            acc[fm][0] = __builtin_amdgcn_mfma_f32_16x16x32_bf16(ar[fm], bf0, acc[fm][0], 0, 0, 0);
            acc[fm][1] = __builtin_amdgcn_mfma_f32_16x16x32_bf16(ar[fm], bf1, acc[fm][1], 0, 0, 0);
        }
    };

    float wr0[16], wr1[16];
    bh8 ar0[4], ar1[4];
    loadWf(0, wr0); loadAf(0, ar0);
    for (int t = 0; t < TSTEPS; t += 2) {
        loadWf(t + 1, wr1); loadAf(t + 1, ar1);    // stage t+1 in flight under comp(t)
        comp(ar0, wr0);
        if (t + 2 < TSTEPS) { loadWf(t + 2, wr0); loadAf(t + 2, ar0); }
        comp(ar1, wr1);
    }

    short* pp = P + (size_t)ks * NTOK * ntot;
#pragma unroll
    for (int fm = 0; fm < 4; ++fm) {
        const int gr0 = wm * 64 + fm * 16 + lkg * 4;
#pragma unroll
        for (int fn = 0; fn < 2; ++fn) {
            const int gc = cb + wn * 32 + fn * 16 + lrow;
#pragma unroll
            for (int q = 0; q < 4; ++q)
                pp[(size_t)(gr0 + q) * ntot + gc] = f2bf(acc[fm][fn][q]);
        }
    }
}

// Sum K-split bf16 partials of Q/K/V; apply interleaved-pair rotary to q and k_new.
__global__ __launch_bounds__(256) void combine_rot(const short* __restrict__ Pq,
                                                   const short* __restrict__ Pk,
                                                   const short* __restrict__ Pv,
                                                   float* __restrict__ qb,
                                                   float* __restrict__ knb,
                                                   float* __restrict__ vnb,
                                                   const float* __restrict__ cosT,
                                                   const float* __restrict__ sinT,
                                                   const int* __restrict__ startp) {
    int gid = blockIdx.x * 256 + threadIdx.x;
    int tok = gid / 3072;
    int pr = gid % 3072;
    int col = pr * 2;
    int start = *startp;
    int pos = start + (tok & (SEQ - 1));
    float a = 0.f, b = 0.f;
    if (col < 4096) {
        const short* base = Pq + (size_t)tok * 4096 + col;
#pragma unroll
        for (int ks = 0; ks < KSPLIT; ++ks) {
            short2 t = *(const short2*)(base + (size_t)ks * NTOK * 4096);
            a += bf2f(t.x); b += bf2f(t.y);
        }
        int i = (col & 127) >> 1;
        float c = cosT[pos * 64 + i], s = sinT[pos * 64 + i];
        qb[(size_t)tok * 4096 + col]     = a * c - b * s;
        qb[(size_t)tok * 4096 + col + 1] = a * s + b * c;
    } else if (col < 5120) {
        int colr = col - 4096;
        const short* base = Pk + (size_t)tok * 1024 + colr;
#pragma unroll
        for (int ks = 0; ks < KSPLIT; ++ks) {
            short2 t = *(const short2*)(base + (size_t)ks * NTOK * 1024);
            a += bf2f(t.x); b += bf2f(t.y);
        }
        int i = (colr & 127) >> 1;
        float c = cosT[pos * 64 + i], s = sinT[pos * 64 + i];
        knb[(size_t)tok * 1024 + colr]     = a * c - b * s;
        knb[(size_t)tok * 1024 + colr + 1] = a * s + b * c;
    } else {
        int colr = col - 5120;
        const short* base = Pv + (size_t)tok * 1024 + colr;
#pragma unroll
        for (int ks = 0; ks < KSPLIT; ++ks) {
            short2 t = *(const short2*)(base + (size_t)ks * NTOK * 1024);
            a += bf2f(t.x); b += bf2f(t.y);
        }
        vnb[(size_t)tok * 1024 + colr]     = a;
        vnb[(size_t)tok * 1024 + colr + 1] = b;
    }
}

// MFMA attention partial pass. grid (ksb, kvh, b) = (16,8,8); block = 256 = 4 waves.
// S^T = mfma(A=K, B=Q^T) with key permutation (softmax + P^T lane-local);
// PV: O^T = mfma(A=V^T, B=P^T).
// T14 STAGE SPLIT: gloadRaw issues pure f32 loads (no cvt) BEFORE compute;
// cvtStore converts+writes LDS AFTER compute, so HBM latency hides under MFMA.
__global__ __launch_bounds__(256) void attn_fused(const float* __restrict__ qb,
                                                  const float* __restrict__ knb,
                                                  const float* __restrict__ vnb,
                                                  const float* __restrict__ ck,
                                                  const float* __restrict__ cv,
                                                  short* __restrict__ Opart,
                                                  float* __restrict__ mpart,
                                                  float* __restrict__ lpart,
                                                  const int* __restrict__ startp) {
    const int ksb = blockIdx.x;
    const int kvh = blockIdx.y;
    const int b   = blockIdx.z;
    const int start = *startp;
    const int klen = start + SEQ;
    const int chunk = (klen + KSA - 1) / KSA;        // 65
    const int bbeg = ksb * chunk;
    const int bend = imin(bbeg + chunk, klen);
    const int tiles = (chunk + 31) >> 5;             // 3, uniform across waves/blocks

    const int tid = threadIdx.x;
    const int w = tid >> 6, lane = tid & 63;
    const int c = lane & 15, g = lane >> 4;
    const int hh = kvh * 4 + w;

    __shared__ __align__(16) _Float16 Ksh[2][16][32][8];   // [buf][dg][slot][8] 16KB
    __shared__ __align__(16) _Float16 Vsh[2][4][128][8];   // [buf][kg][d][key&7] 16KB

    const float scl2 = 0.08838834764831843f * 1.4426950408889634f;  // 1/sqrt(128)*log2e

    // Q fragments (B-operand): qfr[h][j] = Q[tok=c][32h+8g+j] * scl2, f16
    f16x8 qfr[4];
    {
        const float* qp = qb + (size_t)(b * SEQ + c) * 4096 + hh * 128 + 8 * g;
#pragma unroll
        for (int h = 0; h < 4; ++h) {
            float4 a = *(const float4*)(qp + 32 * h);
            float4 b2 = *(const float4*)(qp + 32 * h + 4);
            qfr[h][0] = (_Float16)(a.x * scl2);  qfr[h][1] = (_Float16)(a.y * scl2);
            qfr[h][2] = (_Float16)(a.z * scl2);  qfr[h][3] = (_Float16)(a.w * scl2);
            qfr[h][4] = (_Float16)(b2.x * scl2); qfr[h][5] = (_Float16)(b2.y * scl2);
            qfr[h][6] = (_Float16)(b2.z * scl2); qfr[h][7] = (_Float16)(b2.w * scl2);
        }
    }

    f32x4 acc_o[8];
#pragma unroll
    for (int dm = 0; dm < 8; ++dm) acc_o[dm] = (f32x4){0.f, 0.f, 0.f, 0.f};
    float mrun = -INFINITY, lrun = 0.f;

    // staging geometry: K slot s holds physical key 8*((s>>2)&3)+4*(s>>4)+(s&3)
    const int s_   = tid & 31;
    const int dgA  = tid >> 5;             // 0..7
    const int koffK = 8 * ((s_ >> 2) & 3) + 4 * (s_ >> 4) + (s_ & 3);
    const int kg0 = tid >> 6, d0 = (tid & 63) * 2;

    // RAW f32 staging registers — loads issue here, conversion deferred to cvtStore
    float4 kr0, kr1, kr2, kr3;
    float2 vrw[8];
    auto gloadRaw = [&](int t) {
        const int kp = bbeg + t * 32 + koffK;
        kr0 = (float4){0.f,0.f,0.f,0.f}; kr1 = kr0; kr2 = kr0; kr3 = kr0;
        if (kp < bend) {
            const float* kr = (kp < start)
                ? ck + ((size_t)((b * MAXLEN + kp) * KVH + kvh)) * HD
                : knb + (size_t)(b * SEQ + kp - start) * 1024 + kvh * HD;
            kr0 = *(const float4*)(kr + dgA * 8);
            kr1 = *(const float4*)(kr + dgA * 8 + 4);
            kr2 = *(const float4*)(kr + dgA * 8 + 64);
            kr3 = *(const float4*)(kr + dgA * 8 + 68);
        }
#pragma unroll
        for (int j = 0; j < 8; ++j) {
            const int kpv = bbeg + t * 32 + kg0 * 8 + j;
            vrw[j] = (float2){0.f, 0.f};
            if (kpv < bend) {
                const float* vrp = (kpv < start)
                    ? cv + ((size_t)((b * MAXLEN + kpv) * KVH + kvh)) * HD + d0
                    : vnb + (size_t)(b * SEQ + kpv - start) * 1024 + kvh * HD + d0;
                vrw[j] = *(const float2*)vrp;
            }
        }
    };
    auto cvtStore = [&](int bf) {          // convert-late + LDS write
        f16x8 ka, kb;
        ka[0]=(_Float16)kr0.x; ka[1]=(_Float16)kr0.y; ka[2]=(_Float16)kr0.z; ka[3]=(_Float16)kr0.w;
        ka[4]=(_Float16)kr1.x; ka[5]=(_Float16)kr1.y; ka[6]=(_Float16)kr1.z; ka[7]=(_Float16)kr1.w;
        kb[0]=(_Float16)kr2.x; kb[1]=(_Float16)kr2.y; kb[2]=(_Float16)kr2.z; kb[3]=(_Float16)kr2.w;
        kb[4]=(_Float16)kr3.x; kb[5]=(_Float16)kr3.y; kb[6]=(_Float16)kr3.z; kb[7]=(_Float16)kr3.w;
        *(f16x8*)&Ksh[bf][dgA][s_][0] = ka;
        *(f16x8*)&Ksh[bf][dgA + 8][s_][0] = kb;
        f16x8 w0, w1;
#pragma unroll
        for (int j = 0; j < 8; ++j) { w0[j] = (_Float16)vrw[j].x; w1[j] = (_Float16)vrw[j].y; }
        *(f16x8*)&Vsh[bf][kg0][d0][0] = w0;
        *(f16x8*)&Vsh[bf][kg0][d0 + 1][0] = w1;
    };

    gloadRaw(0);
    cvtStore(0);
    __syncthreads();

    int buf = 0;
    for (int t = 0; t < tiles; ++t) {
        if (t + 1 < tiles) gloadRaw(t + 1);        // pure loads, in flight under compute
        const int nk = imin(32, bend - (bbeg + t * 32));

        f32x4 acc_s[2];
        acc_s[0] = (f32x4){0.f, 0.f, 0.f, 0.f};
        acc_s[1] = (f32x4){0.f, 0.f, 0.f, 0.f};
#pragma unroll
        for (int h = 0; h < 4; ++h) {
#pragma unroll
            for (int m = 0; m < 2; ++m) {
                const f16x8 afr = *(const f16x8*)&Ksh[buf][h * 4 + g][m * 16 + c][0];
                acc_s[m] = __builtin_amdgcn_mfma_f32_16x16x32_f16(afr, qfr[h], acc_s[m], 0, 0, 0);
            }
        }
        float s8[8];
#pragma unroll
        for (int m = 0; m < 2; ++m)
#pragma unroll
            for (int q = 0; q < 4; ++q) s8[m * 4 + q] = acc_s[m][q];
        if (nk < 32) {
#pragma unroll
            for (int jj = 0; jj < 8; ++jj)
                if (8 * g + jj >= nk) s8[jj] = -1e30f;
        }
        float tmax = s8[0];
#pragma unroll
        for (int jj = 1; jj < 8; ++jj) tmax = fmaxf(tmax, s8[jj]);
        tmax = fmaxf(tmax, __shfl_xor(tmax, 16));
        tmax = fmaxf(tmax, __shfl_xor(tmax, 32));     // row max across the 4 g-lanes
        if (__any(tmax > mrun + 11.5f)) {             // sticky max (T13)
            const float mn = fmaxf(mrun, tmax);
            const float fac = fexp2(mrun - mn);
            lrun *= fac;
#pragma unroll
            for (int dm = 0; dm < 8; ++dm) {
                acc_o[dm][0] *= fac; acc_o[dm][1] *= fac;
                acc_o[dm][2] *= fac; acc_o[dm][3] *= fac;
            }
            mrun = mn;
        }
        float pe[8];
#pragma unroll
        for (int jj = 0; jj < 8; ++jj) pe[jj] = fexp2(s8[jj] - mrun);
#pragma unroll
        for (int jj = 0; jj < 8; ++jj) lrun += pe[jj];
        f16x8 bp;
#pragma unroll
        for (int jj = 0; jj < 8; ++jj) bp[jj] = (_Float16)pe[jj];

#pragma unroll
        for (int dm = 0; dm < 8; ++dm) {
            const f16x8 av = *(const f16x8*)&Vsh[buf][g][dm * 16 + c][0];
            acc_o[dm] = __builtin_amdgcn_mfma_f32_16x16x32_f16(av, bp, acc_o[dm], 0, 0, 0);
        }

        if (t + 1 < tiles) cvtStore(buf ^ 1);      // counted wait lands AFTER compute
        __syncthreads();
        buf ^= 1;
    }

    lrun += __shfl_xor(lrun, 16);
    lrun += __shfl_xor(lrun, 32);

    const int base = ((b * KVH + kvh) * KSA + ksb) * 64;
    const int row = w * 16 + c;
#pragma unroll
    for (int dm = 0; dm < 8; ++dm) {
        short4 o4;
        o4.x = f2bf(acc_o[dm][0]); o4.y = f2bf(acc_o[dm][1]);
        o4.z = f2bf(acc_o[dm][2]); o4.w = f2bf(acc_o[dm][3]);
        *(short4*)&Opart[(size_t)(base + row) * 128 + dm * 16 + g * 4] = o4;
    }
    if (g == 0) { mpart[base + row] = mrun; lpart[base + row] = lrun; }
}

// Merge KSA partials -> aob (bf16, out-proj A-layout). m/l are exp2-domain.
__global__ __launch_bounds__(256) void attn_merge(const short* __restrict__ Opart,
                                                  const float* __restrict__ mpart,
                                                  const float* __restrict__ lpart,
                                                  short* __restrict__ aob) {
    const int bkvh = blockIdx.x;
    const int tid = threadIdx.x;
    __shared__ float sf[KSA][64];
    __shared__ float sinvL[64];
    if (tid < 64) {
        const int row = tid;
        float M = -INFINITY;
#pragma unroll
        for (int ks = 0; ks < KSA; ++ks)
            M = fmaxf(M, mpart[(size_t)(bkvh * KSA + ks) * 64 + row]);
        float L = 0.f;
#pragma unroll
        for (int ks = 0; ks < KSA; ++ks) {
            float f = exp2f(mpart[(size_t)(bkvh * KSA + ks) * 64 + row] - M);
            sf[ks][row] = f;
            L += f * lpart[(size_t)(bkvh * KSA + ks) * 64 + row];
        }
        sinvL[row] = 1.f / L;
    }
    __syncthreads();
    const int b = bkvh >> 3, kvh = bkvh & 7;
    for (int e = tid; e < 2048; e += 256) {
        const int row = e >> 5;
        const int d4 = (e & 31) << 2;
        float a0 = 0.f, a1 = 0.f, a2 = 0.f, a3 = 0.f;
#pragma unroll
        for (int ks = 0; ks < KSA; ++ks) {
            const short4 sp = *(const short4*)&Opart[((size_t)(bkvh * KSA + ks) * 64 + row) * 128 + d4];
            const float f = sf[ks][row];
            a0 = fmaf(f, bf2f(sp.x), a0);
            a1 = fmaf(f, bf2f(sp.y), a1);
            a2 = fmaf(f, bf2f(sp.z), a2);
            a3 = fmaf(f, bf2f(sp.w), a3);
        }
        const float iL = sinvL[row];
        a0 *= iL; a1 *= iL; a2 *= iL; a3 *= iL;
        const int hh = kvh * 4 + (row >> 4);
        const int tok = b * SEQ + (row & 15);
        const int col = hh * 128 + d4;
        short4 o;
        o.x = f2bf(a0); o.y = f2bf(a1); o.z = f2bf(a2); o.w = f2bf(a3);
        *(short4*)&aob[((size_t)(col >> 3) * 128 + tok) * 8 + (col & 7)] = o;
    }
}

// Sum the KSPLIT bf16 out-proj partials into f32 d_out.
__global__ __launch_bounds__(256) void sum_parts(const short* __restrict__ P,
                                                 float* __restrict__ out) {
    int i = blockIdx.x * 256 + threadIdx.x;     // over groups of 4 elems, 131072 total
    float a0 = 0.f, a1 = 0.f, a2 = 0.f, a3 = 0.f;
#pragma unroll
    for (int ks = 0; ks < KSPLIT; ++ks) {
        const short4 t = ((const short4*)(P + (size_t)ks * NTOK * 4096))[i];
        a0 += bf2f(t.x); a1 += bf2f(t.y); a2 += bf2f(t.z); a3 += bf2f(t.w);
    }
    ((float4*)out)[i] = make_float4(a0, a1, a2, a3);
}

extern "C" void kernel_launch(void* const* d_in, const int* in_sizes, int n_in,
                              void* d_out, int out_size, void* d_ws, size_t ws_size,
                              hipStream_t stream) {
    const float* x  = (const float*)d_in[0];
    const float* wq = (const float*)d_in[1];
    const float* wk = (const float*)d_in[2];
    const float* wv = (const float*)d_in[3];
    const float* wo = (const float*)d_in[4];
    const float* cs = (const float*)d_in[5];
    const float* sn = (const float*)d_in[6];
    const float* ck = (const float*)d_in[7];
    const float* cv = (const float*)d_in[8];
    const int* startp = (const int*)d_in[9];

    // ws layout (bf16 partials). Opart (16.8MB) overlays Pqb+Pkb+Pvb (12.6MB) plus
    // 4.2MB of pad; all live buffers start after Opart's full extent.
    short* Opart = (short*)d_ws;                              // 64*16*64*128 shorts
    short* Pqb = Opart;                                       // dead by attn time
    short* Pkb = Pqb + (size_t)KSPLIT * NTOK * 4096;
    short* Pvb = Pkb + (size_t)KSPLIT * NTOK * 1024;
    float* qb   = (float*)(Opart + (size_t)64 * KSA * 64 * 128);  // after 16.8MB
    float* knb  = qb + (size_t)NTOK * 4096;
    float* vnb  = knb + (size_t)NTOK * 1024;
    short* xpre = (short*)(vnb + (size_t)NTOK * 1024);
    short* aob  = xpre + (size_t)NTOK * 4096;
    float* mpart = (float*)(aob + (size_t)NTOK * 4096);
    float* lpart = mpart + (size_t)64 * KSA * 64;
    // total ws ~22.3MB

    cvt_x<<<512, 256, 0, stream>>>(x, xpre);
    // QKV: 64 Q col-blocks (NT=64) + 16 K + 16 V, x KSPLIT
    gemm_mfma<<<dim3(96, KSPLIT), 256, 0, stream>>>(xpre, wq, wk, wv, Pqb, Pkb, Pvb);
    combine_rot<<<1536, 256, 0, stream>>>(Pqb, Pkb, Pvb, qb, knb, vnb, cs, sn, startp);
    attn_fused<<<dim3(KSA, KVH, B_), 256, 0, stream>>>(qb, knb, vnb, ck, cv, Opart, mpart, lpart, startp);
    attn_merge<<<64, 256, 0, stream>>>(Opart, mpart, lpart, aob);
    // out-proj: 64 col-blocks (NT=64) x KSPLIT, all take the Q branch (W=wo)
    gemm_mfma<<<dim3(64, KSPLIT), 256, 0, stream>>>(aob, wo, wo, wo, Pqb, Pqb, Pqb);
    sum_parts<<<512, 256, 0, stream>>>(Pqb, (float*)d_out);
}

// Round 3
// 104.110 us; speedup vs baseline: 1.1335x; 1.0187x over previous
//
#include <hip/hip_runtime.h>
#include <math.h>
#include <stdint.h>

#define D 4096
#define H 32
#define KVH 8
#define HD 128
#define B_ 8
#define SEQ 16
#define MAXLEN 2048
#define NTOK 128          // B_*SEQ
#define KSPLIT 8
#define KCH 512           // D / KSPLIT
#define BK 32
#define TSTEPS (KCH / BK) // 16
#define KSA 16            // attention key-split across blocks (merged by attn_merge)

typedef __attribute__((ext_vector_type(8))) short bh8;    // 8 bf16 (4 VGPRs)
typedef __attribute__((ext_vector_type(4))) float f32x4;  // MFMA C/D frag
typedef _Float16 f16x2 __attribute__((ext_vector_type(2)));
typedef _Float16 f16x8 __attribute__((ext_vector_type(8)));

static __device__ __forceinline__ int imin(int a, int b) { return a < b ? a : b; }

static __device__ __forceinline__ short f2bf(float x) {   // RNE f32 -> bf16 bits
    union { float f; uint32_t u; } v; v.f = x;
    uint32_t u = v.u;
    return (short)((u + 0x7fffu + ((u >> 16) & 1u)) >> 16);
}
static __device__ __forceinline__ float bf2f(short b) {
    union { uint32_t u; float f; } v; v.u = ((uint32_t)(uint16_t)b) << 16;
    return v.f;
}

static __device__ __forceinline__ float fexp2(float x) {
#if __has_builtin(__builtin_amdgcn_exp2f)
    return __builtin_amdgcn_exp2f(x);
#else
    return exp2f(x);
#endif
}

// x (128 x 4096 f32) -> bf16 in MFMA A-layout: xp[(kg*128 + row)*8 + j], k = kg*8+j.
__global__ __launch_bounds__(256) void cvt_x(const float* __restrict__ x, short* __restrict__ xp) {
    int i = blockIdx.x * 256 + threadIdx.x;   // 131072 float4s
    int row = i >> 10;
    int c4 = (i & 1023) << 2;                 // col, multiple of 4
    const float4 v = ((const float4*)x)[i];
    short4 o;
    o.x = f2bf(v.x); o.y = f2bf(v.y); o.z = f2bf(v.z); o.w = f2bf(v.w);
    *(short4*)&xp[((size_t)((c4 >> 3) * 128 + row)) * 8 + (c4 & 7)] = o;
}

// C_partial(bf16) = A(128 x K, bf16 pre-laid-out) @ W(K x ntot, f32 row-major).
//
// v4 (wide loads + drain-free barriers): r2 post-mortem — v1/v2 (LDS, wide
// loads, __syncthreads drain) and v3 (reg-direct, narrow dword loads, no
// barriers) all converge to ~2 TB/s. v4 combines the fixed halves of both:
//  - W loads: lane-contiguous float4 (4x256B segments per wave-instr, the
//    m13-copy pattern that reaches 6.3 TB/s), 2 per thread per BK=32 step.
//  - W staged to LDS [col64][k32] (64B col stride -> natural 8-way b128 reads,
//    conflict-free floor, no swizzle); transpose happens in the reg->LDS step.
//  - A-frags: direct per-wave bh8 register loads from xpre (L2-hot).
//  - Sync: raw s_barrier + explicit lgkmcnt(0) ONLY. No __syncthreads ->
//    no vmcnt(0) drain -> global loads stay in flight across barriers (T3/T4).
//    All register data hazards (vmem->cvt, ds_read->MFMA) are compiler-managed
//    counted waits. Only LDS-write visibility needs the lgkm wait.
//  - Depth: W issued 2 tiles ahead (static reg sets, rule #20), cvt+ds_write
//    1 tile later; LDS = 8KB, VGPR ~100.
__global__ __launch_bounds__(256) void gemm_mfma(const short* __restrict__ xp,
                                                 const float* __restrict__ wq,
                                                 const float* __restrict__ wk,
                                                 const float* __restrict__ wv,
                                                 short* __restrict__ Pq,
                                                 short* __restrict__ Pk,
                                                 short* __restrict__ Pv) {
    const int cbid = blockIdx.x;
    const int ks = blockIdx.y;
    const float* W; short* P; int ntot; int cb;
    if (cbid < 64)      { W = wq; P = Pq; ntot = 4096; cb = cbid * 64; }
    else if (cbid < 80) { W = wk; P = Pk; ntot = 1024; cb = (cbid - 64) * 64; }
    else                { W = wv; P = Pv; ntot = 1024; cb = (cbid - 80) * 64; }
    const int tid = threadIdx.x;              // 0..255
    const int lane = tid & 63;
    const int w = tid >> 6;                   // wave 0..3
    const int wm = w >> 1, wn = w & 1;        // wave tile: rows wm*64, cols wn*32
    const int lrow = lane & 15, lkg = lane >> 4;
    const int k0 = ks * KCH;

    __shared__ __align__(16) short Wl[2][64][32];   // [buf][col][k] halves, 4KB/buf

    f32x4 acc[4][2];
#pragma unroll
    for (int fm = 0; fm < 4; ++fm)
#pragma unroll
        for (int fn = 0; fn < 2; ++fn) acc[fm][fn] = (f32x4){0.f, 0.f, 0.f, 0.f};

    // A: per-wave register frags. step t, frag fm: A[row=wm*64+fm*16+lrow][k=(t*4+lkg)*8 + j]
    const short* abase = xp + ((size_t)((k0 >> 3) + lkg) * 128 + wm * 64 + lrow) * 8;
    // W thread map: rows r2, r2+1 of the 32-row step; cols n4..n4+3
    const int n4 = (tid & 15) * 4;
    const int r2 = (tid >> 4) * 2;
    const float* wbase = W + (size_t)(k0 + r2) * ntot + cb + n4;

    auto issueA = [&](int t, bh8 (&ar)[4]) {
        const short* p = abase + (size_t)t * 4096;        // t*4 kgroups * 128 rows * 8
#pragma unroll
        for (int fm = 0; fm < 4; ++fm)
            ar[fm] = *(const bh8*)(p + fm * 128);          // fm*16 rows * 8
    };
    auto issueW = [&](int t, float4& fa, float4& fb) {
        const float* p = wbase + (size_t)t * 32 * ntot;
        fa = *(const float4*)p;                            // row r2
        fb = *(const float4*)(p + ntot);                   // row r2+1
    };
    auto storeW = [&](int bufw, const float4& fa, const float4& fb) {
        *(short2*)&Wl[bufw][n4 + 0][r2] = make_short2(f2bf(fa.x), f2bf(fb.x));
        *(short2*)&Wl[bufw][n4 + 1][r2] = make_short2(f2bf(fa.y), f2bf(fb.y));
        *(short2*)&Wl[bufw][n4 + 2][r2] = make_short2(f2bf(fa.z), f2bf(fb.z));
        *(short2*)&Wl[bufw][n4 + 3][r2] = make_short2(f2bf(fa.w), f2bf(fb.w));
    };
    auto compute = [&](int bufc, const bh8 (&ar)[4]) {
#pragma unroll
        for (int fn = 0; fn < 2; ++fn) {
            const bh8 bfr = *(const bh8*)&Wl[bufc][wn * 32 + fn * 16 + lrow][lkg * 8];
#pragma unroll
            for (int fm = 0; fm < 4; ++fm)
                acc[fm][fn] = __builtin_amdgcn_mfma_f32_16x16x32_bf16(ar[fm], bfr, acc[fm][fn], 0, 0, 0);
        }
    };

    bh8 arE[4], arO[4];
    float4 wEa, wEb, wOa, wOb;                 // W reg sets by tile parity

    issueA(0, arE);
    issueW(0, wEa, wEb);
    issueW(1, wOa, wOb);
    storeW(0, wEa, wEb);                       // compiler: counted vmcnt wait on wE only
    asm volatile("s_waitcnt lgkmcnt(0)" ::: "memory");
    __builtin_amdgcn_s_barrier();

#pragma unroll
    for (int t = 0; t < TSTEPS; ++t) {
        if ((t & 1) == 0) {
            if (t + 1 < TSTEPS) issueA(t + 1, arO);
            if (t + 2 < TSTEPS) issueW(t + 2, wEa, wEb);
            compute(0, arE);
            if (t + 1 < TSTEPS) storeW(1, wOa, wOb);
        } else {
            if (t + 1 < TSTEPS) issueA(t + 1, arE);
            if (t + 2 < TSTEPS) issueW(t + 2, wOa, wOb);
            compute(1, arO);
            if (t + 1 < TSTEPS) storeW(0, wEa, wEb);
        }
        if (t + 1 < TSTEPS) {
            asm volatile("s_waitcnt lgkmcnt(0)" ::: "memory");   // ds_writes visible
            __builtin_amdgcn_s_barrier();                        // raw: vmem NOT drained
        }
    }

    short* pp = P + (size_t)ks * NTOK * ntot;
#pragma unroll
    for (int fm = 0; fm < 4; ++fm) {
        const int gr0 = wm * 64 + fm * 16 + lkg * 4;
#pragma unroll
        for (int fn = 0; fn < 2; ++fn) {
            const int gc = cb + wn * 32 + fn * 16 + lrow;
#pragma unroll
            for (int q = 0; q < 4; ++q)
                pp[(size_t)(gr0 + q) * ntot + gc] = f2bf(acc[fm][fn][q]);
        }
    }
}

// Sum K-split bf16 partials of Q/K/V; apply interleaved-pair rotary to q and k_new.
__global__ __launch_bounds__(256) void combine_rot(const short* __restrict__ Pq,
                                                   const short* __restrict__ Pk,
                                                   const short* __restrict__ Pv,
                                                   float* __restrict__ qb,
                                                   float* __restrict__ knb,
                                                   float* __restrict__ vnb,
                                                   const float* __restrict__ cosT,
                                                   const float* __restrict__ sinT,
                                                   const int* __restrict__ startp) {
    int gid = blockIdx.x * 256 + threadIdx.x;
    int tok = gid / 3072;
    int pr = gid % 3072;
    int col = pr * 2;
    int start = *startp;
    int pos = start + (tok & (SEQ - 1));
    float a = 0.f, b = 0.f;
    if (col < 4096) {
        const short* base = Pq + (size_t)tok * 4096 + col;
#pragma unroll
        for (int ks = 0; ks < KSPLIT; ++ks) {
            short2 t = *(const short2*)(base + (size_t)ks * NTOK * 4096);
            a += bf2f(t.x); b += bf2f(t.y);
        }
        int i = (col & 127) >> 1;
        float c = cosT[pos * 64 + i], s = sinT[pos * 64 + i];
        qb[(size_t)tok * 4096 + col]     = a * c - b * s;
        qb[(size_t)tok * 4096 + col + 1] = a * s + b * c;
    } else if (col < 5120) {
        int colr = col - 4096;
        const short* base = Pk + (size_t)tok * 1024 + colr;
#pragma unroll
        for (int ks = 0; ks < KSPLIT; ++ks) {
            short2 t = *(const short2*)(base + (size_t)ks * NTOK * 1024);
            a += bf2f(t.x); b += bf2f(t.y);
        }
        int i = (colr & 127) >> 1;
        float c = cosT[pos * 64 + i], s = sinT[pos * 64 + i];
        knb[(size_t)tok * 1024 + colr]     = a * c - b * s;
        knb[(size_t)tok * 1024 + colr + 1] = a * s + b * c;
    } else {
        int colr = col - 5120;
        const short* base = Pv + (size_t)tok * 1024 + colr;
#pragma unroll
        for (int ks = 0; ks < KSPLIT; ++ks) {
            short2 t = *(const short2*)(base + (size_t)ks * NTOK * 1024);
            a += bf2f(t.x); b += bf2f(t.y);
        }
        vnb[(size_t)tok * 1024 + colr]     = a;
        vnb[(size_t)tok * 1024 + colr + 1] = b;
    }
}

// MFMA attention partial pass. grid (ksb, kvh, b) = (16,8,8); block = 256 = 4 waves.
// S^T = mfma(A=K, B=Q^T) with key permutation (softmax + P^T lane-local);
// PV: O^T = mfma(A=V^T, B=P^T).
// T14 STAGE SPLIT: gloadRaw issues pure f32 loads (no cvt) BEFORE compute;
// cvtStore converts+writes LDS AFTER compute, so HBM latency hides under MFMA.
__global__ __launch_bounds__(256) void attn_fused(const float* __restrict__ qb,
                                                  const float* __restrict__ knb,
                                                  const float* __restrict__ vnb,
                                                  const float* __restrict__ ck,
                                                  const float* __restrict__ cv,
                                                  short* __restrict__ Opart,
                                                  float* __restrict__ mpart,
                                                  float* __restrict__ lpart,
                                                  const int* __restrict__ startp) {
    const int ksb = blockIdx.x;
    const int kvh = blockIdx.y;
    const int b   = blockIdx.z;
    const int start = *startp;
    const int klen = start + SEQ;
    const int chunk = (klen + KSA - 1) / KSA;        // 65
    const int bbeg = ksb * chunk;
    const int bend = imin(bbeg + chunk, klen);
    const int tiles = (chunk + 31) >> 5;             // 3, uniform across waves/blocks

    const int tid = threadIdx.x;
    const int w = tid >> 6, lane = tid & 63;
    const int c = lane & 15, g = lane >> 4;
    const int hh = kvh * 4 + w;

    __shared__ __align__(16) _Float16 Ksh[2][16][32][8];   // [buf][dg][slot][8] 16KB
    __shared__ __align__(16) _Float16 Vsh[2][4][128][8];   // [buf][kg][d][key&7] 16KB

    const float scl2 = 0.08838834764831843f * 1.4426950408889634f;  // 1/sqrt(128)*log2e

    // Q fragments (B-operand): qfr[h][j] = Q[tok=c][32h+8g+j] * scl2, f16
    f16x8 qfr[4];
    {
        const float* qp = qb + (size_t)(b * SEQ + c) * 4096 + hh * 128 + 8 * g;
#pragma unroll
        for (int h = 0; h < 4; ++h) {
            float4 a = *(const float4*)(qp + 32 * h);
            float4 b2 = *(const float4*)(qp + 32 * h + 4);
            qfr[h][0] = (_Float16)(a.x * scl2);  qfr[h][1] = (_Float16)(a.y * scl2);
            qfr[h][2] = (_Float16)(a.z * scl2);  qfr[h][3] = (_Float16)(a.w * scl2);
            qfr[h][4] = (_Float16)(b2.x * scl2); qfr[h][5] = (_Float16)(b2.y * scl2);
            qfr[h][6] = (_Float16)(b2.z * scl2); qfr[h][7] = (_Float16)(b2.w * scl2);
        }
    }

    f32x4 acc_o[8];
#pragma unroll
    for (int dm = 0; dm < 8; ++dm) acc_o[dm] = (f32x4){0.f, 0.f, 0.f, 0.f};
    float mrun = -INFINITY, lrun = 0.f;

    // staging geometry: K slot s holds physical key 8*((s>>2)&3)+4*(s>>4)+(s&3)
    const int s_   = tid & 31;
    const int dgA  = tid >> 5;             // 0..7
    const int koffK = 8 * ((s_ >> 2) & 3) + 4 * (s_ >> 4) + (s_ & 3);
    const int kg0 = tid >> 6, d0 = (tid & 63) * 2;

    // RAW f32 staging registers — loads issue here, conversion deferred to cvtStore
    float4 kr0, kr1, kr2, kr3;
    float2 vrw[8];
    auto gloadRaw = [&](int t) {
        const int kp = bbeg + t * 32 + koffK;
        kr0 = (float4){0.f,0.f,0.f,0.f}; kr1 = kr0; kr2 = kr0; kr3 = kr0;
        if (kp < bend) {
            const float* kr = (kp < start)
                ? ck + ((size_t)((b * MAXLEN + kp) * KVH + kvh)) * HD
                : knb + (size_t)(b * SEQ + kp - start) * 1024 + kvh * HD;
            kr0 = *(const float4*)(kr + dgA * 8);
            kr1 = *(const float4*)(kr + dgA * 8 + 4);
            kr2 = *(const float4*)(kr + dgA * 8 + 64);
            kr3 = *(const float4*)(kr + dgA * 8 + 68);
        }
#pragma unroll
        for (int j = 0; j < 8; ++j) {
            const int kpv = bbeg + t * 32 + kg0 * 8 + j;
            vrw[j] = (float2){0.f, 0.f};
            if (kpv < bend) {
                const float* vrp = (kpv < start)
                    ? cv + ((size_t)((b * MAXLEN + kpv) * KVH + kvh)) * HD + d0
                    : vnb + (size_t)(b * SEQ + kpv - start) * 1024 + kvh * HD + d0;
                vrw[j] = *(const float2*)vrp;
            }
        }
    };
    auto cvtStore = [&](int bf) {          // convert-late + LDS write
        f16x8 ka, kb;
        ka[0]=(_Float16)kr0.x; ka[1]=(_Float16)kr0.y; ka[2]=(_Float16)kr0.z; ka[3]=(_Float16)kr0.w;
        ka[4]=(_Float16)kr1.x; ka[5]=(_Float16)kr1.y; ka[6]=(_Float16)kr1.z; ka[7]=(_Float16)kr1.w;
        kb[0]=(_Float16)kr2.x; kb[1]=(_Float16)kr2.y; kb[2]=(_Float16)kr2.z; kb[3]=(_Float16)kr2.w;
        kb[4]=(_Float16)kr3.x; kb[5]=(_Float16)kr3.y; kb[6]=(_Float16)kr3.z; kb[7]=(_Float16)kr3.w;
        *(f16x8*)&Ksh[bf][dgA][s_][0] = ka;
        *(f16x8*)&Ksh[bf][dgA + 8][s_][0] = kb;
        f16x8 w0, w1;
#pragma unroll
        for (int j = 0; j < 8; ++j) { w0[j] = (_Float16)vrw[j].x; w1[j] = (_Float16)vrw[j].y; }
        *(f16x8*)&Vsh[bf][kg0][d0][0] = w0;
        *(f16x8*)&Vsh[bf][kg0][d0 + 1][0] = w1;
    };

    gloadRaw(0);
    cvtStore(0);
    __syncthreads();

    int buf = 0;
    for (int t = 0; t < tiles; ++t) {
        if (t + 1 < tiles) gloadRaw(t + 1);        // pure loads, in flight under compute
        const int nk = imin(32, bend - (bbeg + t * 32));

        f32x4 acc_s[2];
        acc_s[0] = (f32x4){0.f, 0.f, 0.f, 0.f};
        acc_s[1] = (f32x4){0.f, 0.f, 0.f, 0.f};
#pragma unroll
        for (int h = 0; h < 4; ++h) {
#pragma unroll
            for (int m = 0; m < 2; ++m) {
                const f16x8 afr = *(const f16x8*)&Ksh[buf][h * 4 + g][m * 16 + c][0];
                acc_s[m] = __builtin_amdgcn_mfma_f32_16x16x32_f16(afr, qfr[h], acc_s[m], 0, 0, 0);
            }
        }
        float s8[8];
#pragma unroll
        for (int m = 0; m < 2; ++m)
#pragma unroll
            for (int q = 0; q < 4; ++q) s8[m * 4 + q] = acc_s[m][q];
        if (nk < 32) {
#pragma unroll
            for (int jj = 0; jj < 8; ++jj)
                if (8 * g + jj >= nk) s8[jj] = -1e30f;
        }
        float tmax = s8[0];
#pragma unroll
        for (int jj = 1; jj < 8; ++jj) tmax = fmaxf(tmax, s8[jj]);
        tmax = fmaxf(tmax, __shfl_xor(tmax, 16));
        tmax = fmaxf(tmax, __shfl_xor(tmax, 32));     // row max across the 4 g-lanes
        if (__any(tmax > mrun + 11.5f)) {             // sticky max (T13)
            const float mn = fmaxf(mrun, tmax);
            const float fac = fexp2(mrun - mn);
            lrun *= fac;
#pragma unroll
            for (int dm = 0; dm < 8; ++dm) {
                acc_o[dm][0] *= fac; acc_o[dm][1] *= fac;
                acc_o[dm][2] *= fac; acc_o[dm][3] *= fac;
            }
            mrun = mn;
        }
        float pe[8];
#pragma unroll
        for (int jj = 0; jj < 8; ++jj) pe[jj] = fexp2(s8[jj] - mrun);
#pragma unroll
        for (int jj = 0; jj < 8; ++jj) lrun += pe[jj];
        f16x8 bp;
#pragma unroll
        for (int jj = 0; jj < 8; ++jj) bp[jj] = (_Float16)pe[jj];

#pragma unroll
        for (int dm = 0; dm < 8; ++dm) {
            const f16x8 av = *(const f16x8*)&Vsh[buf][g][dm * 16 + c][0];
            acc_o[dm] = __builtin_amdgcn_mfma_f32_16x16x32_f16(av, bp, acc_o[dm], 0, 0, 0);
        }

        if (t + 1 < tiles) cvtStore(buf ^ 1);      // counted wait lands AFTER compute
        __syncthreads();
        buf ^= 1;
    }

    lrun += __shfl_xor(lrun, 16);
    lrun += __shfl_xor(lrun, 32);

    const int base = ((b * KVH + kvh) * KSA + ksb) * 64;
    const int row = w * 16 + c;
#pragma unroll
    for (int dm = 0; dm < 8; ++dm) {
        short4 o4;
        o4.x = f2bf(acc_o[dm][0]); o4.y = f2bf(acc_o[dm][1]);
        o4.z = f2bf(acc_o[dm][2]); o4.w = f2bf(acc_o[dm][3]);
        *(short4*)&Opart[(size_t)(base + row) * 128 + dm * 16 + g * 4] = o4;
    }
    if (g == 0) { mpart[base + row] = mrun; lpart[base + row] = lrun; }
}

// Merge KSA partials -> aob (bf16, out-proj A-layout). m/l are exp2-domain.
__global__ __launch_bounds__(256) void attn_merge(const short* __restrict__ Opart,
                                                  const float* __restrict__ mpart,
                                                  const float* __restrict__ lpart,
                                                  short* __restrict__ aob) {
    const int bkvh = blockIdx.x;
    const int tid = threadIdx.x;
    __shared__ float sf[KSA][64];
    __shared__ float sinvL[64];
    if (tid < 64) {
        const int row = tid;
        float M = -INFINITY;
#pragma unroll
        for (int ks = 0; ks < KSA; ++ks)
            M = fmaxf(M, mpart[(size_t)(bkvh * KSA + ks) * 64 + row]);
        float L = 0.f;
#pragma unroll
        for (int ks = 0; ks < KSA; ++ks) {
            float f = exp2f(mpart[(size_t)(bkvh * KSA + ks) * 64 + row] - M);
            sf[ks][row] = f;
            L += f * lpart[(size_t)(bkvh * KSA + ks) * 64 + row];
        }
        sinvL[row] = 1.f / L;
    }
    __syncthreads();
    const int b = bkvh >> 3, kvh = bkvh & 7;
    for (int e = tid; e < 2048; e += 256) {
        const int row = e >> 5;
        const int d4 = (e & 31) << 2;
        float a0 = 0.f, a1 = 0.f, a2 = 0.f, a3 = 0.f;
#pragma unroll
        for (int ks = 0; ks < KSA; ++ks) {
            const short4 sp = *(const short4*)&Opart[((size_t)(bkvh * KSA + ks) * 64 + row) * 128 + d4];
            const float f = sf[ks][row];
            a0 = fmaf(f, bf2f(sp.x), a0);
            a1 = fmaf(f, bf2f(sp.y), a1);
            a2 = fmaf(f, bf2f(sp.z), a2);
            a3 = fmaf(f, bf2f(sp.w), a3);
        }
        const float iL = sinvL[row];
        a0 *= iL; a1 *= iL; a2 *= iL; a3 *= iL;
        const int hh = kvh * 4 + (row >> 4);
        const int tok = b * SEQ + (row & 15);
        const int col = hh * 128 + d4;
        short4 o;
        o.x = f2bf(a0); o.y = f2bf(a1); o.z = f2bf(a2); o.w = f2bf(a3);
        *(short4*)&aob[((size_t)(col >> 3) * 128 + tok) * 8 + (col & 7)] = o;
    }
}

// Sum the KSPLIT bf16 out-proj partials into f32 d_out.
__global__ __launch_bounds__(256) void sum_parts(const short* __restrict__ P,
                                                 float* __restrict__ out) {
    int i = blockIdx.x * 256 + threadIdx.x;     // over groups of 4 elems, 131072 total
    float a0 = 0.f, a1 = 0.f, a2 = 0.f, a3 = 0.f;
#pragma unroll
    for (int ks = 0; ks < KSPLIT; ++ks) {
        const short4 t = ((const short4*)(P + (size_t)ks * NTOK * 4096))[i];
        a0 += bf2f(t.x); a1 += bf2f(t.y); a2 += bf2f(t.z); a3 += bf2f(t.w);
    }
    ((float4*)out)[i] = make_float4(a0, a1, a2, a3);
}

extern "C" void kernel_launch(void* const* d_in, const int* in_sizes, int n_in,
                              void* d_out, int out_size, void* d_ws, size_t ws_size,
                              hipStream_t stream) {
    const float* x  = (const float*)d_in[0];
    const float* wq = (const float*)d_in[1];
    const float* wk = (const float*)d_in[2];
    const float* wv = (const float*)d_in[3];
    const float* wo = (const float*)d_in[4];
    const float* cs = (const float*)d_in[5];
    const float* sn = (const float*)d_in[6];
    const float* ck = (const float*)d_in[7];
    const float* cv = (const float*)d_in[8];
    const int* startp = (const int*)d_in[9];

    // ws layout (bf16 partials). Opart (16.8MB) overlays Pqb+Pkb+Pvb (12.6MB) plus
    // 4.2MB of pad; all live buffers start after Opart's full extent.
    short* Opart = (short*)d_ws;                              // 64*16*64*128 shorts
    short* Pqb = Opart;                                       // dead by attn time
    short* Pkb = Pqb + (size_t)KSPLIT * NTOK * 4096;
    short* Pvb = Pkb + (size_t)KSPLIT * NTOK * 1024;
    float* qb   = (float*)(Opart + (size_t)64 * KSA * 64 * 128);  // after 16.8MB
    float* knb  = qb + (size_t)NTOK * 4096;
    float* vnb  = knb + (size_t)NTOK * 1024;
    short* xpre = (short*)(vnb + (size_t)NTOK * 1024);
    short* aob  = xpre + (size_t)NTOK * 4096;
    float* mpart = (float*)(aob + (size_t)NTOK * 4096);
    float* lpart = mpart + (size_t)64 * KSA * 64;
    // total ws ~22.3MB

    cvt_x<<<512, 256, 0, stream>>>(x, xpre);
    // QKV: 64 Q col-blocks (NT=64) + 16 K + 16 V, x KSPLIT
    gemm_mfma<<<dim3(96, KSPLIT), 256, 0, stream>>>(xpre, wq, wk, wv, Pqb, Pkb, Pvb);
    combine_rot<<<1536, 256, 0, stream>>>(Pqb, Pkb, Pvb, qb, knb, vnb, cs, sn, startp);
    attn_fused<<<dim3(KSA, KVH, B_), 256, 0, stream>>>(qb, knb, vnb, ck, cv, Opart, mpart, lpart, startp);
    attn_merge<<<64, 256, 0, stream>>>(Opart, mpart, lpart, aob);
    // out-proj: 64 col-blocks (NT=64) x KSPLIT, all take the Q branch (W=wo)
    gemm_mfma<<<dim3(64, KSPLIT), 256, 0, stream>>>(aob, wo, wo, wo, Pqb, Pqb, Pqb);
    sum_parts<<<512, 256, 0, stream>>>(Pqb, (float*)d_out);
}